// Round 4
// baseline (129.854 us; speedup 1.0000x reference)
//
#include <hip/hip_runtime.h>
#include <math.h>

// Problem constants (reference: N=256, S=1, stimulus 144x256, retina 144x256)
#define NB    256
#define IMG_H 144
#define IMG_W 256
#define HR    144
#define WR    256
#define FDIM  16
#define DDIM  128

#define FOV_HALF_RAD 0.6544984694978736f   // 0.5 * 75deg in rad
#define GELU_GAMMA   1.7015043497085571f
#define OUT_OF_RANGE 10.0f

typedef float f32x4 __attribute__((ext_vector_type(4)));  // native vector for nontemporal builtin

// jax.nn.gelu default is approximate=True (tanh form)
__device__ __forceinline__ float gelu_gamma(float x) {
    const float k0 = 0.7978845608028654f;  // sqrt(2/pi)
    const float k1 = 0.044715f;
    float t = tanhf(k0 * (x + k1 * x * x * x));
    return 0.5f * x * (1.0f + t) * GELU_GAMMA;
}

// One block per batch element; 128 threads = hidden dim.
__global__ void __launch_bounds__(DDIM) mlp_rmat_kernel(
    const float* __restrict__ persp,  // [NB, FDIM]
    const float* __restrict__ W1,     // [FDIM, DDIM]
    const float* __restrict__ b1,     // [DDIM]
    const float* __restrict__ W2,     // [DDIM, DDIM]
    const float* __restrict__ b2,     // [DDIM]
    const float* __restrict__ Wp,     // [DDIM, 3]
    const float* __restrict__ bp,     // [3]
    float* __restrict__ Rout)         // [NB, 9]
{
    const int n = blockIdx.x;
    const int d = threadIdx.x;

    __shared__ float sh1[DDIM];
    __shared__ float sh2[DDIM];
    __shared__ float ang[3];

    float acc = b1[d];
#pragma unroll
    for (int f = 0; f < FDIM; ++f)
        acc += persp[n * FDIM + f] * W1[f * DDIM + d];
    sh1[d] = gelu_gamma(acc);
    __syncthreads();

    float acc2 = b2[d];
#pragma unroll 8
    for (int k = 0; k < DDIM; ++k)
        acc2 += sh1[k] * W2[k * DDIM + d];
    sh2[d] = gelu_gamma(acc2);
    __syncthreads();

    if (d < 3) {
        float a = bp[d];
#pragma unroll 8
        for (int k = 0; k < DDIM; ++k)
            a += sh2[k] * Wp[k * 3 + d];
        ang[d] = a;
    }
    __syncthreads();

    if (d == 0) {
        float cx = cosf(ang[0]), sx = sinf(ang[0]);
        float cy = cosf(ang[1]), sy = sinf(ang[1]);
        float cz = cosf(ang[2]), sz = sinf(ang[2]);
        float* R = Rout + n * 9;
        R[0] = cz * cy;  R[1] = cz * sy * sx - sz * cx;  R[2] = cz * sy * cx + sz * sx;
        R[3] = sz * cy;  R[4] = sz * sy * sx + cz * cx;  R[5] = sz * sy * cx - cz * sx;
        R[6] = -sy;      R[7] = cy * sx;                 R[8] = cy * cx;
    }
}

__device__ __forceinline__ float fetch_px(const float* __restrict__ img, int yi, int xi) {
    bool valid = ((unsigned)xi < IMG_W) & ((unsigned)yi < IMG_H);
    return valid ? img[yi * IMG_W + xi] : 0.0f;
}

// 4 pixels per thread along x. Block = 256 threads covers 4 rows x 256 cols
// of one image. grid = (HR/4, NB). 16 independent gathers in flight per
// thread (vs 4) to hide L2/HBM gather latency; float4 nontemporal store.
__global__ void __launch_bounds__(256) retina_sample_kernel(
    const float* __restrict__ stim,   // [NB, 1, IMG_H, IMG_W]
    const float* __restrict__ Rmat,   // [NB, 9]
    float* __restrict__ out)          // [NB, 1, HR, WR]
{
    const int tid = threadIdx.x;
    const int n   = blockIdx.y;
    const int h   = blockIdx.x * 4 + (tid >> 6);   // 4 rows per block
    const int w0  = (tid & 63) * 4;                // 4 consecutive x per thread

    // Block-uniform rotation matrix (scalar loads)
    const float* Rn = Rmat + n * 9;
    const float r0 = Rn[0], r1 = Rn[1], r2 = Rn[2];
    const float r3 = Rn[3], r4 = Rn[4], r5 = Rn[5];
    const float r6 = Rn[6], r7 = Rn[7], r8 = Rn[8];

    const float gy  = (2.0f * h + 1.0f - 144.0f) * (1.0f / 256.0f);
    const float ayv = gy * FOV_HALF_RAD;
    const float ay2 = ayv * ayv;

    const float* __restrict__ img = stim + (size_t)n * (IMG_H * IMG_W);

    float px_[4], py_[4];
    int   x0_[4], y0_[4];
    float v00[4], v01[4], v10[4], v11[4];

#pragma unroll
    for (int j = 0; j < 4; ++j) {
        const float gx  = (2.0f * (w0 + j) + 1.0f - 256.0f) * (1.0f / 256.0f);
        const float axv = gx * FOV_HALF_RAD;
        const float t   = axv * axv + ay2;          // a^2, t <= 0.56

        // sinc(a): even Taylor in t, |err| ~1e-8 on this range
        float sc = fmaf(t, 2.7557319e-6f, -1.9841270e-4f);
        sc = fmaf(t, sc,  8.3333333e-3f);
        sc = fmaf(t, sc, -1.6666667e-1f);
        sc = fmaf(t, sc,  1.0f);

        // cos(a): even Taylor in t
        float ca = fmaf(t, 2.4801587e-5f, -1.3888889e-3f);
        ca = fmaf(t, ca,  4.1666667e-2f);
        ca = fmaf(t, ca, -0.5f);
        ca = fmaf(t, ca,  1.0f);

        const float dx = sc * axv, dy = sc * ayv, dz = ca;

        const float rx = r0 * dx + r1 * dy + r2 * dz;
        const float ry = r3 * dx + r4 * dy + r5 * dz;
        const float rz = r6 * dx + r7 * dy + r8 * dz;

        const float inv = __builtin_amdgcn_rcpf(rz);
        const bool safe = rz > 0.001f;
        const float gxp = safe ? rx * inv : OUT_OF_RANGE;
        const float gyp = safe ? ry * inv : OUT_OF_RANGE;

        px_[j] = fmaf(gxp, 256.0f, (float)(IMG_W - 1)) * 0.5f;
        py_[j] = fmaf(gyp, 256.0f, (float)(IMG_H - 1)) * 0.5f;
        x0_[j] = (int)floorf(px_[j]);
        y0_[j] = (int)floorf(py_[j]);
    }

    // Issue all 16 gathers back-to-back (max outstanding loads)
#pragma unroll
    for (int j = 0; j < 4; ++j) {
        v00[j] = fetch_px(img, y0_[j],     x0_[j]);
        v01[j] = fetch_px(img, y0_[j],     x0_[j] + 1);
        v10[j] = fetch_px(img, y0_[j] + 1, x0_[j]);
        v11[j] = fetch_px(img, y0_[j] + 1, x0_[j] + 1);
    }

    f32x4 res;
#pragma unroll
    for (int j = 0; j < 4; ++j) {
        const float wx = px_[j] - floorf(px_[j]);
        const float wy = py_[j] - floorf(py_[j]);
        const float top = v00[j] * (1.0f - wx) + v01[j] * wx;
        const float bot = v10[j] * (1.0f - wx) + v11[j] * wx;
        res[j] = top * (1.0f - wy) + bot * wy;
    }

    // Coalesced 16B/lane nontemporal store (don't pollute L2; out is write-once)
    f32x4* dst = (f32x4*)(out + ((size_t)n * HR + h) * WR + w0);
    __builtin_nontemporal_store(res, dst);
}

extern "C" void kernel_launch(void* const* d_in, const int* in_sizes, int n_in,
                              void* d_out, int out_size, void* d_ws, size_t ws_size,
                              hipStream_t stream) {
    const float* stimulus    = (const float*)d_in[0]; // [256,1,144,256]
    const float* perspective = (const float*)d_in[1]; // [256,16]
    const float* W1          = (const float*)d_in[2]; // [16,128]
    const float* b1          = (const float*)d_in[3]; // [128]
    const float* W2          = (const float*)d_in[4]; // [128,128]
    const float* b2          = (const float*)d_in[5]; // [128]
    const float* Wp          = (const float*)d_in[6]; // [128,3]
    const float* bp          = (const float*)d_in[7]; // [3]
    float* out = (float*)d_out;

    float* Rmat = (float*)d_ws; // 256*9 floats

    mlp_rmat_kernel<<<NB, DDIM, 0, stream>>>(
        perspective, W1, b1, W2, b2, Wp, bp, Rmat);

    dim3 grid(HR / 4, NB);
    retina_sample_kernel<<<grid, 256, 0, stream>>>(stimulus, Rmat, out);
}

// Round 5
// 127.567 us; speedup vs baseline: 1.0179x; 1.0179x over previous
//
#include <hip/hip_runtime.h>
#include <math.h>

// Problem constants (reference: N=256, S=1, stimulus 144x256, retina 144x256)
#define NB    256
#define IMG_H 144
#define IMG_W 256
#define IMG_ELEMS (IMG_H * IMG_W)   // 36864 floats = 144 KiB (fits 160 KiB LDS)
#define HR    144
#define WR    256
#define FDIM  16
#define DDIM  128

#define FOV_HALF_RAD 0.6544984694978736f   // 0.5 * 75deg in rad
#define GELU_GAMMA   1.7015043497085571f
#define OUT_OF_RANGE 10.0f

typedef float f32x4 __attribute__((ext_vector_type(4)));

// jax.nn.gelu default is approximate=True (tanh form)
__device__ __forceinline__ float gelu_gamma(float x) {
    const float k0 = 0.7978845608028654f;  // sqrt(2/pi)
    const float k1 = 0.044715f;
    float t = tanhf(k0 * (x + k1 * x * x * x));
    return 0.5f * x * (1.0f + t) * GELU_GAMMA;
}

// One block per batch element; 128 threads = hidden dim.
__global__ void __launch_bounds__(DDIM) mlp_rmat_kernel(
    const float* __restrict__ persp,  // [NB, FDIM]
    const float* __restrict__ W1,     // [FDIM, DDIM]
    const float* __restrict__ b1,     // [DDIM]
    const float* __restrict__ W2,     // [DDIM, DDIM]
    const float* __restrict__ b2,     // [DDIM]
    const float* __restrict__ Wp,     // [DDIM, 3]
    const float* __restrict__ bp,     // [3]
    float* __restrict__ Rout)         // [NB, 9]
{
    const int n = blockIdx.x;
    const int d = threadIdx.x;

    __shared__ float sh1[DDIM];
    __shared__ float sh2[DDIM];
    __shared__ float ang[3];

    float acc = b1[d];
#pragma unroll
    for (int f = 0; f < FDIM; ++f)
        acc += persp[n * FDIM + f] * W1[f * DDIM + d];
    sh1[d] = gelu_gamma(acc);
    __syncthreads();

    float acc2 = b2[d];
#pragma unroll 8
    for (int k = 0; k < DDIM; ++k)
        acc2 += sh1[k] * W2[k * DDIM + d];
    sh2[d] = gelu_gamma(acc2);
    __syncthreads();

    if (d < 3) {
        float a = bp[d];
#pragma unroll 8
        for (int k = 0; k < DDIM; ++k)
            a += sh2[k] * Wp[k * 3 + d];
        ang[d] = a;
    }
    __syncthreads();

    if (d == 0) {
        float cx = cosf(ang[0]), sx = sinf(ang[0]);
        float cy = cosf(ang[1]), sy = sinf(ang[1]);
        float cz = cosf(ang[2]), sz = sinf(ang[2]);
        float* R = Rout + n * 9;
        R[0] = cz * cy;  R[1] = cz * sy * sx - sz * cx;  R[2] = cz * sy * cx + sz * sx;
        R[3] = sz * cy;  R[4] = sz * sy * sx + cz * cx;  R[5] = sz * sy * cx - cz * sx;
        R[6] = -sy;      R[7] = cy * sx;                 R[8] = cy * cx;
    }
}

// One block per image. 1024 threads stage the whole 144 KiB image into LDS
// (coalesced float4), then gather bilinear corners from LDS (ds_read_b32,
// lane-spread across banks -> ~conflict-free) and store coalesced float4.
// HBM traffic = exactly one coalesced image read + one output write.
__global__ void __launch_bounds__(1024, 1) retina_sample_kernel(
    const float* __restrict__ stim,   // [NB, 1, IMG_H, IMG_W]
    const float* __restrict__ Rmat,   // [NB, 9]
    float* __restrict__ out)          // [NB, 1, HR, WR]
{
    __shared__ float simg[IMG_ELEMS];   // 144 KiB of the 160 KiB LDS

    const int tid = threadIdx.x;
    const int n   = blockIdx.x;

    const float* __restrict__ img = stim + (size_t)n * IMG_ELEMS;

    // ---- stage image -> LDS: 9216 float4 groups, 9 per thread, coalesced
    {
        const f32x4* __restrict__ src = (const f32x4*)img;
        f32x4* dstl = (f32x4*)simg;
#pragma unroll
        for (int p = 0; p < 9; ++p)
            dstl[tid + p * 1024] = src[tid + p * 1024];
    }

    // Block-uniform rotation matrix (scalar loads, overlap with staging)
    const float* Rn = Rmat + n * 9;
    const float r0 = Rn[0], r1 = Rn[1], r2 = Rn[2];
    const float r3 = Rn[3], r4 = Rn[4], r5 = Rn[5];
    const float r6 = Rn[6], r7 = Rn[7], r8 = Rn[8];

    __syncthreads();

    // ---- gather phase: 9 groups of 4 consecutive pixels per thread
#pragma unroll
    for (int p = 0; p < 9; ++p) {
        const int g   = tid + p * 1024;   // float4-group index in [0, 9216)
        const int px0 = g * 4;            // linear pixel index (4 | px0, so one row)
        const int h   = px0 >> 8;         // /256
        const int w0  = px0 & 255;

        const float gy  = (2.0f * h + 1.0f - 144.0f) * (1.0f / 256.0f);
        const float ayv = gy * FOV_HALF_RAD;
        const float ay2 = ayv * ayv;

        f32x4 res;
#pragma unroll
        for (int j = 0; j < 4; ++j) {
            const float gx  = (2.0f * (w0 + j) + 1.0f - 256.0f) * (1.0f / 256.0f);
            const float axv = gx * FOV_HALF_RAD;
            const float t   = axv * axv + ay2;          // a^2, t <= 0.56

            // sinc(a): even Taylor in t, |err| ~1e-8 on this range
            float sc = fmaf(t, 2.7557319e-6f, -1.9841270e-4f);
            sc = fmaf(t, sc,  8.3333333e-3f);
            sc = fmaf(t, sc, -1.6666667e-1f);
            sc = fmaf(t, sc,  1.0f);

            // cos(a): even Taylor in t
            float ca = fmaf(t, 2.4801587e-5f, -1.3888889e-3f);
            ca = fmaf(t, ca,  4.1666667e-2f);
            ca = fmaf(t, ca, -0.5f);
            ca = fmaf(t, ca,  1.0f);

            const float dx = sc * axv, dy = sc * ayv, dz = ca;

            const float rx = r0 * dx + r1 * dy + r2 * dz;
            const float ry = r3 * dx + r4 * dy + r5 * dz;
            const float rz = r6 * dx + r7 * dy + r8 * dz;

            const float inv = __builtin_amdgcn_rcpf(rz);
            const bool safe = rz > 0.001f;
            const float gxp = safe ? rx * inv : OUT_OF_RANGE;
            const float gyp = safe ? ry * inv : OUT_OF_RANGE;

            const float px = fmaf(gxp, 256.0f, (float)(IMG_W - 1)) * 0.5f;
            const float py = fmaf(gyp, 256.0f, (float)(IMG_H - 1)) * 0.5f;

            const float x0f = floorf(px), y0f = floorf(py);
            const float wx = px - x0f, wy = py - y0f;
            const int x0 = (int)x0f, y0 = (int)y0f;
            const int x1 = x0 + 1,   y1 = y0 + 1;

            // clamp addresses (stay inside LDS), zero OOB after read
            const int xc0 = min(max(x0, 0), IMG_W - 1);
            const int xc1 = min(max(x1, 0), IMG_W - 1);
            const int yc0 = min(max(y0, 0), IMG_H - 1);
            const int yc1 = min(max(y1, 0), IMG_H - 1);

            const bool vx0 = (unsigned)x0 < IMG_W, vx1 = (unsigned)x1 < IMG_W;
            const bool vy0 = (unsigned)y0 < IMG_H, vy1 = (unsigned)y1 < IMG_H;

            float v00 = simg[yc0 * IMG_W + xc0];
            float v01 = simg[yc0 * IMG_W + xc1];
            float v10 = simg[yc1 * IMG_W + xc0];
            float v11 = simg[yc1 * IMG_W + xc1];
            v00 = (vx0 & vy0) ? v00 : 0.0f;
            v01 = (vx1 & vy0) ? v01 : 0.0f;
            v10 = (vx0 & vy1) ? v10 : 0.0f;
            v11 = (vx1 & vy1) ? v11 : 0.0f;

            const float top = v00 * (1.0f - wx) + v01 * wx;
            const float bot = v10 * (1.0f - wx) + v11 * wx;
            res[j] = top * (1.0f - wy) + bot * wy;
        }

        // Coalesced 16B/lane nontemporal store
        f32x4* dst = (f32x4*)(out + (size_t)n * IMG_ELEMS + px0);
        __builtin_nontemporal_store(res, dst);
    }
}

extern "C" void kernel_launch(void* const* d_in, const int* in_sizes, int n_in,
                              void* d_out, int out_size, void* d_ws, size_t ws_size,
                              hipStream_t stream) {
    const float* stimulus    = (const float*)d_in[0]; // [256,1,144,256]
    const float* perspective = (const float*)d_in[1]; // [256,16]
    const float* W1          = (const float*)d_in[2]; // [16,128]
    const float* b1          = (const float*)d_in[3]; // [128]
    const float* W2          = (const float*)d_in[4]; // [128,128]
    const float* b2          = (const float*)d_in[5]; // [128]
    const float* Wp          = (const float*)d_in[6]; // [128,3]
    const float* bp          = (const float*)d_in[7]; // [3]
    float* out = (float*)d_out;

    float* Rmat = (float*)d_ws; // 256*9 floats

    mlp_rmat_kernel<<<NB, DDIM, 0, stream>>>(
        perspective, W1, b1, W2, b2, Wp, bp, Rmat);

    retina_sample_kernel<<<NB, 1024, 0, stream>>>(stimulus, Rmat, out);
}

// Round 6
// 118.726 us; speedup vs baseline: 1.0937x; 1.0745x over previous
//
#include <hip/hip_runtime.h>
#include <math.h>

// Problem constants (reference: N=256, S=1, stimulus 144x256, retina 144x256)
#define NB    256
#define IMG_H 144
#define IMG_W 256
#define IMG_ELEMS (IMG_H * IMG_W)   // 36864 floats = 144 KiB
#define LDS_STRIDE 260              // padded row stride (floats): breaks row-bank alias, keeps 16B align
#define HR    144
#define WR    256
#define FDIM  16
#define DDIM  128

#define FOV_HALF_RAD 0.6544984694978736f   // 0.5 * 75deg in rad
#define GELU_GAMMA   1.7015043497085571f
#define OUT_OF_RANGE 10.0f

typedef float f32x4 __attribute__((ext_vector_type(4)));

// jax.nn.gelu default is approximate=True (tanh form)
__device__ __forceinline__ float gelu_gamma(float x) {
    const float k0 = 0.7978845608028654f;  // sqrt(2/pi)
    const float k1 = 0.044715f;
    float t = tanhf(k0 * (x + k1 * x * x * x));
    return 0.5f * x * (1.0f + t) * GELU_GAMMA;
}

// One block per batch element; 128 threads = hidden dim.
__global__ void __launch_bounds__(DDIM) mlp_rmat_kernel(
    const float* __restrict__ persp,  // [NB, FDIM]
    const float* __restrict__ W1,     // [FDIM, DDIM]
    const float* __restrict__ b1,     // [DDIM]
    const float* __restrict__ W2,     // [DDIM, DDIM]
    const float* __restrict__ b2,     // [DDIM]
    const float* __restrict__ Wp,     // [DDIM, 3]
    const float* __restrict__ bp,     // [3]
    float* __restrict__ Rout)         // [NB, 9]
{
    const int n = blockIdx.x;
    const int d = threadIdx.x;

    __shared__ float sh1[DDIM];
    __shared__ float sh2[DDIM];
    __shared__ float ang[3];

    float acc = b1[d];
#pragma unroll
    for (int f = 0; f < FDIM; ++f)
        acc += persp[n * FDIM + f] * W1[f * DDIM + d];
    sh1[d] = gelu_gamma(acc);
    __syncthreads();

    float acc2 = b2[d];
#pragma unroll 8
    for (int k = 0; k < DDIM; ++k)
        acc2 += sh1[k] * W2[k * DDIM + d];
    sh2[d] = gelu_gamma(acc2);
    __syncthreads();

    if (d < 3) {
        float a = bp[d];
#pragma unroll 8
        for (int k = 0; k < DDIM; ++k)
            a += sh2[k] * Wp[k * 3 + d];
        ang[d] = a;
    }
    __syncthreads();

    if (d == 0) {
        float cx = cosf(ang[0]), sx = sinf(ang[0]);
        float cy = cosf(ang[1]), sy = sinf(ang[1]);
        float cz = cosf(ang[2]), sz = sinf(ang[2]);
        float* R = Rout + n * 9;
        R[0] = cz * cy;  R[1] = cz * sy * sx - sz * cx;  R[2] = cz * sy * cx + sz * sx;
        R[3] = sz * cy;  R[4] = sz * sy * sx + cz * cx;  R[5] = sz * sy * cx - cz * sx;
        R[6] = -sy;      R[7] = cy * sx;                 R[8] = cy * cx;
    }
}

// One block per image. 1024 threads stage the image into LDS with a PADDED
// row stride (260 floats: +4 -> adjacent rows offset by 4 banks, so the
// v00/v10 same-bank collision of stride-256 is gone; 16B alignment kept for
// f32x4 staging writes). launch_bounds(1024,4) = 4 waves/EU -> 128-VGPR
// budget so the unrolled gather loop keeps multiple pixel-groups' ds_reads
// in flight (R5 had 52 VGPRs and serialized).
__global__ void __launch_bounds__(1024, 4) retina_sample_kernel(
    const float* __restrict__ stim,   // [NB, 1, IMG_H, IMG_W]
    const float* __restrict__ Rmat,   // [NB, 9]
    float* __restrict__ out)          // [NB, 1, HR, WR]
{
    __shared__ float simg[IMG_H * LDS_STRIDE];   // 149.8 KiB of 160 KiB

    const int tid = threadIdx.x;
    const int n   = blockIdx.x;

    // Block-uniform rotation matrix (scalar loads, issued before staging)
    const float* Rn = Rmat + n * 9;
    const float r0 = Rn[0], r1 = Rn[1], r2 = Rn[2];
    const float r3 = Rn[3], r4 = Rn[4], r5 = Rn[5];
    const float r6 = Rn[6], r7 = Rn[7], r8 = Rn[8];

    const float* __restrict__ img = stim + (size_t)n * IMG_ELEMS;

    // ---- stage image -> LDS (padded layout): 9216 float4 groups, 9/thread
    {
        const f32x4* __restrict__ src = (const f32x4*)img;
#pragma unroll
        for (int p = 0; p < 9; ++p) {
            const int g   = tid + p * 1024;   // f32x4-group index
            const int row = g >> 6;           // 64 groups per row
            const int c4  = g & 63;
            *(f32x4*)&simg[row * LDS_STRIDE + c4 * 4] = src[g];
        }
    }
    __syncthreads();

    // ---- gather phase: 9 groups of 4 consecutive pixels per thread
#pragma unroll
    for (int p = 0; p < 9; ++p) {
        const int g   = tid + p * 1024;
        const int px0 = g * 4;            // linear pixel index (one row)
        const int h   = px0 >> 8;
        const int w0  = px0 & 255;

        const float gy  = (2.0f * h + 1.0f - 144.0f) * (1.0f / 256.0f);
        const float ayv = gy * FOV_HALF_RAD;
        const float ay2 = ayv * ayv;

        float wx_[4], wy_[4];
        int a00[4], a01[4], a10[4], a11[4];
        bool m00[4], m01[4], m10[4], m11[4];

#pragma unroll
        for (int j = 0; j < 4; ++j) {
            const float gx  = (2.0f * (w0 + j) + 1.0f - 256.0f) * (1.0f / 256.0f);
            const float axv = gx * FOV_HALF_RAD;
            const float t   = axv * axv + ay2;          // a^2, t <= 0.56

            // sinc(a): even Taylor in t, |err| ~1e-8 on this range
            float sc = fmaf(t, 2.7557319e-6f, -1.9841270e-4f);
            sc = fmaf(t, sc,  8.3333333e-3f);
            sc = fmaf(t, sc, -1.6666667e-1f);
            sc = fmaf(t, sc,  1.0f);

            // cos(a): even Taylor in t
            float ca = fmaf(t, 2.4801587e-5f, -1.3888889e-3f);
            ca = fmaf(t, ca,  4.1666667e-2f);
            ca = fmaf(t, ca, -0.5f);
            ca = fmaf(t, ca,  1.0f);

            const float dx = sc * axv, dy = sc * ayv, dz = ca;

            const float rx = r0 * dx + r1 * dy + r2 * dz;
            const float ry = r3 * dx + r4 * dy + r5 * dz;
            const float rz = r6 * dx + r7 * dy + r8 * dz;

            const float inv = __builtin_amdgcn_rcpf(rz);
            const bool safe = rz > 0.001f;
            const float gxp = safe ? rx * inv : OUT_OF_RANGE;
            const float gyp = safe ? ry * inv : OUT_OF_RANGE;

            const float px = fmaf(gxp, 256.0f, (float)(IMG_W - 1)) * 0.5f;
            const float py = fmaf(gyp, 256.0f, (float)(IMG_H - 1)) * 0.5f;

            const float x0f = floorf(px), y0f = floorf(py);
            wx_[j] = px - x0f;
            wy_[j] = py - y0f;
            const int x0 = (int)x0f, y0 = (int)y0f;
            const int x1 = x0 + 1,   y1 = y0 + 1;

            const int xc0 = min(max(x0, 0), IMG_W - 1);
            const int xc1 = min(max(x1, 0), IMG_W - 1);
            const int yc0 = min(max(y0, 0), IMG_H - 1);
            const int yc1 = min(max(y1, 0), IMG_H - 1);

            m00[j] = ((unsigned)x0 < IMG_W) & ((unsigned)y0 < IMG_H);
            m01[j] = ((unsigned)x1 < IMG_W) & ((unsigned)y0 < IMG_H);
            m10[j] = ((unsigned)x0 < IMG_W) & ((unsigned)y1 < IMG_H);
            m11[j] = ((unsigned)x1 < IMG_W) & ((unsigned)y1 < IMG_H);

            a00[j] = yc0 * LDS_STRIDE + xc0;
            a01[j] = yc0 * LDS_STRIDE + xc1;
            a10[j] = yc1 * LDS_STRIDE + xc0;
            a11[j] = yc1 * LDS_STRIDE + xc1;
        }

        // issue all 16 LDS reads back-to-back
        float v00[4], v01[4], v10[4], v11[4];
#pragma unroll
        for (int j = 0; j < 4; ++j) {
            v00[j] = simg[a00[j]];
            v01[j] = simg[a01[j]];
            v10[j] = simg[a10[j]];
            v11[j] = simg[a11[j]];
        }

        f32x4 res;
#pragma unroll
        for (int j = 0; j < 4; ++j) {
            const float c00 = m00[j] ? v00[j] : 0.0f;
            const float c01 = m01[j] ? v01[j] : 0.0f;
            const float c10 = m10[j] ? v10[j] : 0.0f;
            const float c11 = m11[j] ? v11[j] : 0.0f;
            const float top = c00 * (1.0f - wx_[j]) + c01 * wx_[j];
            const float bot = c10 * (1.0f - wx_[j]) + c11 * wx_[j];
            res[j] = top * (1.0f - wy_[j]) + bot * wy_[j];
        }

        f32x4* dst = (f32x4*)(out + (size_t)n * IMG_ELEMS + px0);
        __builtin_nontemporal_store(res, dst);
    }
}

extern "C" void kernel_launch(void* const* d_in, const int* in_sizes, int n_in,
                              void* d_out, int out_size, void* d_ws, size_t ws_size,
                              hipStream_t stream) {
    const float* stimulus    = (const float*)d_in[0]; // [256,1,144,256]
    const float* perspective = (const float*)d_in[1]; // [256,16]
    const float* W1          = (const float*)d_in[2]; // [16,128]
    const float* b1          = (const float*)d_in[3]; // [128]
    const float* W2          = (const float*)d_in[4]; // [128,128]
    const float* b2          = (const float*)d_in[5]; // [128]
    const float* Wp          = (const float*)d_in[6]; // [128,3]
    const float* bp          = (const float*)d_in[7]; // [3]
    float* out = (float*)d_out;

    float* Rmat = (float*)d_ws; // 256*9 floats

    mlp_rmat_kernel<<<NB, DDIM, 0, stream>>>(
        perspective, W1, b1, W2, b2, Wp, bp, Rmat);

    retina_sample_kernel<<<NB, 1024, 0, stream>>>(stimulus, Rmat, out);
}